// Round 10
// baseline (332.523 us; speedup 1.0000x reference)
//
#include <hip/hip_runtime.h>
#include <math.h>

#define N_NODES 50000
#define N_EDGES 800000
#define SCAN_BLOCKS ((N_NODES + 1023) / 1024)   // 49
#define BSH 7                                    // 128 nodes per bucket
#define BNODES 128
#define NBKT ((N_NODES + BNODES - 1) / BNODES)   // 391
#define EPW 4096                                 // edges per workgroup in bucketA
#define NWG_A ((N_EDGES + EPW - 1) / EPW)        // 196
#define NXCD 8

typedef _Float16 half4_t __attribute__((ext_vector_type(4)));
typedef _Float16 half8_t __attribute__((ext_vector_type(8)));
typedef float floatx4 __attribute__((ext_vector_type(4)));

// ---------------------------------------------------------------------------
// Workspace layout:
//   flag     : int[64]
//   cnt      : int[50048]    in-degree (no self-loop)
//   dinv     : float[50048]  rsqrt(1+deg)
//   rowptr   : int[50056]    global exclusive scan
//   blocksum : int[64]
//   bcur     : int[448]      per-bucket reservation cursors
//   ep       : uint[800000]  packed edges (src | dst<<16)
//   ep2      : uint[800000]  bucket-grouped packed edges
//   csr_src  : ushort[800000]
//   Wt1/2/3  : fp16 W^T
//   h        : fp16[50000*128]
//   agg      : fp16[50000*128]
// ---------------------------------------------------------------------------

__device__ __forceinline__ void load_edge(const void* ei, int is64, int e, int& s, int& d) {
    if (is64) {
        const long long* q = (const long long*)ei;
        s = (int)q[e];
        d = (int)q[N_EDGES + e];
    } else {
        const int* q = (const int*)ei;
        s = q[e];
        d = q[N_EDGES + e];
    }
}

// Merged: zero cnt + detect i64 + weight cast/transpose.
__global__ void init_k(const int* ei, int* flag, int* cnt,
                       const float* __restrict__ W1, const float* __restrict__ W2,
                       const float* __restrict__ W3,
                       _Float16* __restrict__ Wt1, _Float16* __restrict__ Wt2,
                       _Float16* __restrict__ Wt3) {
    int i = blockIdx.x * 256 + threadIdx.x;
    if (i < 50048) cnt[i] = 0;
    if (i == 0) {
        int orr = 0;
        for (int j = 0; j < 16; ++j) orr |= ei[2 * j + 1];
        *flag = (orr == 0) ? 1 : 0;
    }
    if (i < 16384) {
        int k = i >> 7, c = i & 127;           // W1[128][128]
        Wt1[c * 128 + k] = (_Float16)W1[i];
    } else if (i < 32768) {
        int j = i - 16384;
        int k = j >> 7, c = j & 127;           // W2[128][128]
        Wt2[c * 128 + k] = (_Float16)W2[j];
    } else if (i < 40960) {
        int j = i - 32768;
        int k = j >> 6, c = j & 63;            // W3[128][64]
        Wt3[c * 128 + k] = (_Float16)W3[j];
    }
}

// Histogram + compact the edge list into 4B packed form (node ids < 2^16).
__global__ void deg_compact_k(const void* ei, const int* flag, int* cnt,
                              unsigned int* __restrict__ ep) {
    int e = blockIdx.x * 256 + threadIdx.x;
    if (e >= N_EDGES) return;
    int is64 = *flag;
    int s, d;
    load_edge(ei, is64, e, s, d);
    ep[e] = (unsigned int)s | ((unsigned int)d << 16);
    atomicAdd(&cnt[d], 1);
}

// Phase 1: per-block local exclusive scan of cnt -> rowptr; dinv fused.
__global__ __launch_bounds__(1024) void scan_pass1_k(const int* __restrict__ cnt,
                                                     int* __restrict__ rowptr,
                                                     int* __restrict__ blocksum,
                                                     float* __restrict__ dinv) {
    __shared__ int buf[1024];
    int tid = threadIdx.x;
    int i = blockIdx.x * 1024 + tid;
    int v = (i < N_NODES) ? cnt[i] : 0;
    if (i < N_NODES) dinv[i] = rsqrtf(1.0f + (float)v);
    buf[tid] = v;
    __syncthreads();
#pragma unroll
    for (int off = 1; off < 1024; off <<= 1) {
        int t = (tid >= off) ? buf[tid - off] : 0;
        __syncthreads();
        buf[tid] += t;
        __syncthreads();
    }
    int incl = buf[tid];
    if (i < N_NODES) rowptr[i] = incl - v;   // local exclusive
    if (tid == 1023) blocksum[blockIdx.x] = incl;
}

// Phase 2+3 merged: every block redundantly wave-scans the 49 block sums,
// then applies its offsets; emits per-bucket reservation cursors.
__global__ void scan_pass23_k(int* __restrict__ rowptr, const int* __restrict__ blocksum,
                              int* __restrict__ bcur) {
    __shared__ int soff[SCAN_BLOCKS];
    int tid = threadIdx.x;
    if (tid < 64) {
        int v = (tid < SCAN_BLOCKS) ? blocksum[tid] : 0;
        int incl = v;
#pragma unroll
        for (int off = 1; off < 64; off <<= 1) {
            int t = __shfl_up(incl, off);
            if (tid >= off) incl += t;
        }
        if (tid < SCAN_BLOCKS) soff[tid] = incl - v;
    }
    __syncthreads();
    int i = blockIdx.x * 256 + tid;
    if (i < N_NODES) {
        int v = rowptr[i] + soff[i >> 10];
        rowptr[i] = v;
        if ((i & (BNODES - 1)) == 0) bcur[i >> BSH] = v;
    }
    if (blockIdx.x == 0 && tid == 0)
        rowptr[N_NODES] = soff[SCAN_BLOCKS - 1] + blocksum[SCAN_BLOCKS - 1];
}

// Bucket pass A: group edges by dst-bucket (128 nodes / bucket).
__global__ __launch_bounds__(256) void bucketA_k(const unsigned int* __restrict__ ep,
                                                 int* bcur,
                                                 unsigned int* __restrict__ ep2) {
    __shared__ int hist[NBKT];
    __shared__ int gofs[NBKT];
    __shared__ int lcur[NBKT];
    int tid = threadIdx.x;
    for (int i = tid; i < NBKT; i += 256) { hist[i] = 0; lcur[i] = 0; }
    __syncthreads();
    int base = blockIdx.x * EPW;
    unsigned int pv[EPW / 256];
#pragma unroll
    for (int j = 0; j < EPW / 256; ++j) {
        int e = base + j * 256 + tid;
        unsigned int p = (e < N_EDGES) ? ep[e] : 0xFFFFFFFFu;
        pv[j] = p;
        if (p != 0xFFFFFFFFu) atomicAdd(&hist[(p >> 16) >> BSH], 1);
    }
    __syncthreads();
    for (int i = tid; i < NBKT; i += 256)
        gofs[i] = hist[i] ? atomicAdd(&bcur[i], hist[i]) : 0;
    __syncthreads();
#pragma unroll
    for (int j = 0; j < EPW / 256; ++j) {
        unsigned int p = pv[j];
        if (p == 0xFFFFFFFFu) continue;
        int b = (int)((p >> 16) >> BSH);
        int pos = gofs[b] + atomicAdd(&lcur[b], 1);
        ep2[pos] = p;
    }
}

// Bucket pass B: one wg per bucket; node cursors in LDS; private 4KB store region.
__global__ __launch_bounds__(256) void bucketB_k(const unsigned int* __restrict__ ep2,
                                                 const int* __restrict__ rowptr,
                                                 unsigned short* __restrict__ csr_src) {
    __shared__ int lcur[BNODES];
    int b = blockIdx.x;
    int lo = b << BSH;
    int hi = min(lo + BNODES, N_NODES);
    int tid = threadIdx.x;
    if (tid < hi - lo) lcur[tid] = rowptr[lo + tid];
    __syncthreads();
    int beg = rowptr[lo];
    int end = rowptr[hi];
    for (int j = beg + tid; j < end; j += 256) {
        unsigned int p = ep2[j];
        int s = (int)(p & 0xFFFFu);
        int d = (int)(p >> 16);
        int slot = atomicAdd(&lcur[d - lo], 1);
        csr_src[slot] = (unsigned short)s;
    }
}

// hs[N][DOUT] = (relu(A)[N][128] @ W[128][DOUT]) * dinv[row], fp16 out.
template <int DOUT, bool RELU, typename TIN>
__global__ __launch_bounds__(256) void mm_mfma_k(const TIN* __restrict__ A,
                                                 const _Float16* __restrict__ Wt,
                                                 const float* __restrict__ dinv,
                                                 _Float16* __restrict__ C) {
    constexpr int AST = 128 + 8;   // padded fp16 row stride (bank-spread)
    __shared__ _Float16 As[64 * AST];
    __shared__ _Float16 Ws[DOUT * AST];
    const int tid = threadIdx.x;
    const int rowBase = blockIdx.x * 64;

    if constexpr (sizeof(TIN) == 4) {
        for (int i = tid; i < 64 * 32; i += 256) {       // float4 granules
            int r = i >> 5;
            int k4 = (i & 31) * 4;
            int gr = rowBase + r;
            float4 v = make_float4(0.f, 0.f, 0.f, 0.f);
            if (gr < N_NODES) v = *(const float4*)((const float*)A + (size_t)gr * 128 + k4);
            if (RELU) {
                v.x = fmaxf(v.x, 0.f); v.y = fmaxf(v.y, 0.f);
                v.z = fmaxf(v.z, 0.f); v.w = fmaxf(v.w, 0.f);
            }
            half4_t hv;
            hv[0] = (_Float16)v.x; hv[1] = (_Float16)v.y;
            hv[2] = (_Float16)v.z; hv[3] = (_Float16)v.w;
            *(half4_t*)&As[r * AST + k4] = hv;
        }
    } else {
        for (int i = tid; i < 64 * 16; i += 256) {       // half8 granules
            int r = i >> 4;
            int k8 = (i & 15) * 8;
            int gr = rowBase + r;
            half8_t v = {};
            if (gr < N_NODES) v = *(const half8_t*)((const _Float16*)A + (size_t)gr * 128 + k8);
            if (RELU) {
#pragma unroll
                for (int j = 0; j < 8; ++j) v[j] = (v[j] > (_Float16)0) ? v[j] : (_Float16)0;
            }
            *(half8_t*)&As[r * AST + k8] = v;
        }
    }
    for (int i = tid; i < DOUT * 16; i += 256) {
        int r = i >> 4;
        int k8 = (i & 15) * 8;
        *(half8_t*)&Ws[r * AST + k8] = *(const half8_t*)(Wt + r * 128 + k8);
    }
    __syncthreads();

    const int wid = tid >> 6;
    const int lane = tid & 63;
    const int l15 = lane & 15;
    const int lk = (lane >> 4) * 8;
    const int wrow = wid * 16;

    floatx4 acc[DOUT / 16];
#pragma unroll
    for (int t = 0; t < DOUT / 16; ++t) acc[t] = (floatx4){0.f, 0.f, 0.f, 0.f};

#pragma unroll
    for (int kc = 0; kc < 4; ++kc) {
        half8_t af = *(const half8_t*)&As[(wrow + l15) * AST + kc * 32 + lk];
#pragma unroll
        for (int ct = 0; ct < DOUT / 16; ++ct) {
            half8_t bf = *(const half8_t*)&Ws[(ct * 16 + l15) * AST + kc * 32 + lk];
            acc[ct] = __builtin_amdgcn_mfma_f32_16x16x32_f16(af, bf, acc[ct], 0, 0, 0);
        }
    }

    int rloc = wrow + (lane >> 4) * 4;
#pragma unroll
    for (int q = 0; q < 4; ++q) {
        int gr = rowBase + rloc + q;
        if (gr < N_NODES) {
            float dn = dinv[gr];
#pragma unroll
            for (int ct = 0; ct < DOUT / 16; ++ct) {
                C[(size_t)gr * DOUT + ct * 16 + l15] = (_Float16)(acc[ct][q] * dn);
            }
        }
    }
}

// Pull aggregation, XCD-column-partitioned:
//   out[n, cols] = dinv[n] * (sum_e hs[src[e], cols] + hs[n, cols]) + b[cols]
// CBF features per column block; colblock = blockIdx % 8 -> per-XCD L2 slice.
template <int DOUT, int CBF, bool F16OUT>
__global__ __launch_bounds__(256) void gather_k(const _Float16* __restrict__ h,
                                                const int* __restrict__ rowptr,
                                                const unsigned short* __restrict__ csr_src,
                                                const float* __restrict__ dinv,
                                                const float* __restrict__ b,
                                                void* __restrict__ out) {
    constexpr int TPN = CBF / 8;       // lanes per node (each lane: 8 feats)
    constexpr int NPB = 256 / TPN;     // nodes per block
    constexpr int NCB = DOUT / CBF;    // column blocks (8)
    int cb = blockIdx.x % NCB;
    int gb = blockIdx.x / NCB;
    int n = gb * NPB + threadIdx.x / TPN;
    int li = threadIdx.x % TPN;
    if (n >= N_NODES) return;
    int co = cb * CBF + li * 8;        // feature offset of this lane
    const _Float16* hp = h + co;
    int beg = rowptr[n];
    int end = rowptr[n + 1];
    float acc[8], acc2[8];
#pragma unroll
    for (int j = 0; j < 8; ++j) { acc[j] = 0.f; acc2[j] = 0.f; }
    int e = beg;
    for (; e + 4 <= end; e += 4) {
        int s0 = csr_src[e];
        int s1 = csr_src[e + 1];
        int s2 = csr_src[e + 2];
        int s3 = csr_src[e + 3];
        half8_t v0 = *(const half8_t*)(hp + (size_t)s0 * DOUT);
        half8_t v1 = *(const half8_t*)(hp + (size_t)s1 * DOUT);
        half8_t v2 = *(const half8_t*)(hp + (size_t)s2 * DOUT);
        half8_t v3 = *(const half8_t*)(hp + (size_t)s3 * DOUT);
#pragma unroll
        for (int j = 0; j < 8; ++j) {
            acc[j] += (float)v0[j];
            acc2[j] += (float)v1[j];
            acc[j] += (float)v2[j];
            acc2[j] += (float)v3[j];
        }
    }
    for (; e < end; ++e) {
        int s0 = csr_src[e];
        half8_t v0 = *(const half8_t*)(hp + (size_t)s0 * DOUT);
#pragma unroll
        for (int j = 0; j < 8; ++j) acc[j] += (float)v0[j];
    }
    float dn = dinv[n];
    half8_t hv = *(const half8_t*)(hp + (size_t)n * DOUT);
    float4 bv0 = *(const float4*)(b + co);
    float4 bv1 = *(const float4*)(b + co + 4);
    float r[8];
    r[0] = (acc[0] + acc2[0] + (float)hv[0]) * dn + bv0.x;
    r[1] = (acc[1] + acc2[1] + (float)hv[1]) * dn + bv0.y;
    r[2] = (acc[2] + acc2[2] + (float)hv[2]) * dn + bv0.z;
    r[3] = (acc[3] + acc2[3] + (float)hv[3]) * dn + bv0.w;
    r[4] = (acc[4] + acc2[4] + (float)hv[4]) * dn + bv1.x;
    r[5] = (acc[5] + acc2[5] + (float)hv[5]) * dn + bv1.y;
    r[6] = (acc[6] + acc2[6] + (float)hv[6]) * dn + bv1.z;
    r[7] = (acc[7] + acc2[7] + (float)hv[7]) * dn + bv1.w;
    if constexpr (F16OUT) {
        half8_t o;
#pragma unroll
        for (int j = 0; j < 8; ++j) o[j] = (_Float16)r[j];
        *(half8_t*)((_Float16*)out + (size_t)n * DOUT + co) = o;
    } else {
        float* op = (float*)out + (size_t)n * DOUT + co;
        *(float4*)op = make_float4(r[0], r[1], r[2], r[3]);
        *(float4*)(op + 4) = make_float4(r[4], r[5], r[6], r[7]);
    }
}

extern "C" void kernel_launch(void* const* d_in, const int* in_sizes, int n_in,
                              void* d_out, int out_size, void* d_ws, size_t ws_size,
                              hipStream_t stream) {
    const float* x  = (const float*)d_in[0];
    const void*  ei = d_in[1];
    const float* W1 = (const float*)d_in[2];
    const float* b1 = (const float*)d_in[3];
    const float* W2 = (const float*)d_in[4];
    const float* b2 = (const float*)d_in[5];
    const float* W3 = (const float*)d_in[6];
    const float* b3 = (const float*)d_in[7];
    float* out = (float*)d_out;

    char* wsb = (char*)d_ws;
    size_t o = 0;
    int*            flag     = (int*)(wsb + o); o += 64 * 4;
    int*            cnt      = (int*)(wsb + o); o += 50048 * 4;
    float*          dinv     = (float*)(wsb + o); o += 50048 * 4;
    int*            rowptr   = (int*)(wsb + o); o += 50056 * 4;
    int*            blocksum = (int*)(wsb + o); o += 64 * 4;
    int*            bcur     = (int*)(wsb + o); o += 448 * 4;
    unsigned int*   ep       = (unsigned int*)(wsb + o); o += (size_t)N_EDGES * 4;
    unsigned int*   ep2      = (unsigned int*)(wsb + o); o += (size_t)N_EDGES * 4;
    unsigned short* csr_src  = (unsigned short*)(wsb + o); o += (size_t)N_EDGES * 2;
    _Float16*       Wt1      = (_Float16*)(wsb + o); o += 128 * 128 * 2;
    _Float16*       Wt2      = (_Float16*)(wsb + o); o += 128 * 128 * 2;
    _Float16*       Wt3      = (_Float16*)(wsb + o); o += 64 * 128 * 2;
    _Float16*       h        = (_Float16*)(wsb + o); o += (size_t)N_NODES * 128 * 2;
    _Float16*       agg      = (_Float16*)(wsb + o);

    const int NB_N = (N_NODES + 255) / 256;   // 196
    const int NB_E = (N_EDGES + 255) / 256;   // 3125
    const int MMB  = (N_NODES + 63) / 64;     // 782
    const int G128 = NXCD * ((N_NODES + 127) / 128);   // 8*391
    const int G64  = NXCD * ((N_NODES + 255) / 256);   // 8*196

    // ---- graph preprocessing (once; reused by all 3 layers) ----
    init_k<<<NB_N, 256, 0, stream>>>((const int*)ei, flag, cnt, W1, W2, W3, Wt1, Wt2, Wt3);
    deg_compact_k<<<NB_E, 256, 0, stream>>>(ei, flag, cnt, ep);
    scan_pass1_k<<<SCAN_BLOCKS, 1024, 0, stream>>>(cnt, rowptr, blocksum, dinv);
    scan_pass23_k<<<NB_N, 256, 0, stream>>>(rowptr, blocksum, bcur);
    bucketA_k<<<NWG_A, 256, 0, stream>>>(ep, bcur, ep2);
    bucketB_k<<<NBKT, 256, 0, stream>>>(ep2, rowptr, csr_src);

    // ---- layer 1 ----
    mm_mfma_k<128, false, float><<<MMB, 256, 0, stream>>>(x, Wt1, dinv, h);
    gather_k<128, 16, true><<<G128, 256, 0, stream>>>(h, rowptr, csr_src, dinv, b1, agg);

    // ---- layer 2 ----
    mm_mfma_k<128, true, _Float16><<<MMB, 256, 0, stream>>>(agg, Wt2, dinv, h);
    gather_k<128, 16, true><<<G128, 256, 0, stream>>>(h, rowptr, csr_src, dinv, b2, agg);

    // ---- layer 3 (to d_out, f32) ----
    mm_mfma_k<64, true, _Float16><<<MMB, 256, 0, stream>>>(agg, Wt3, dinv, h);
    gather_k<64, 8, false><<<G64, 256, 0, stream>>>(h, rowptr, csr_src, dinv, b3, out);
}

// Round 11
// 293.698 us; speedup vs baseline: 1.1322x; 1.1322x over previous
//
#include <hip/hip_runtime.h>
#include <math.h>

#define N_NODES 50000
#define N_EDGES 800000
#define SCAN_BLOCKS ((N_NODES + 1023) / 1024)   // 49
#define BSH 7                                    // 128 nodes per bucket
#define BNODES 128
#define NBKT ((N_NODES + BNODES - 1) / BNODES)   // 391
#define EPW 4096                                 // edges per workgroup in bucketA
#define NWG_A ((N_EDGES + EPW - 1) / EPW)        // 196

typedef _Float16 half4_t __attribute__((ext_vector_type(4)));
typedef _Float16 half8_t __attribute__((ext_vector_type(8)));
typedef float floatx4 __attribute__((ext_vector_type(4)));

// ---------------------------------------------------------------------------
// Workspace layout:
//   flag     : int[64]
//   cnt      : int[50048]    in-degree (no self-loop)
//   dinv     : float[50048]  rsqrt(1+deg)
//   rowptr   : int[50056]    global exclusive scan
//   blocksum : int[64]
//   bcur     : int[448]      per-bucket reservation cursors
//   ep       : uint[800000]  packed edges (src | dst<<16)
//   ep2      : uint[800000]  bucket-grouped packed edges
//   csr_src  : ushort[800000]
//   Wt1/2/3  : fp16 W^T
//   h        : fp16[50000*128]
//   agg      : fp16[50000*128]
// ---------------------------------------------------------------------------

__device__ __forceinline__ void load_edge(const void* ei, int is64, int e, int& s, int& d) {
    if (is64) {
        const long long* q = (const long long*)ei;
        s = (int)q[e];
        d = (int)q[N_EDGES + e];
    } else {
        const int* q = (const int*)ei;
        s = q[e];
        d = q[N_EDGES + e];
    }
}

// Merged: zero cnt + detect i64 + weight cast/transpose.
__global__ void init_k(const int* ei, int* flag, int* cnt,
                       const float* __restrict__ W1, const float* __restrict__ W2,
                       const float* __restrict__ W3,
                       _Float16* __restrict__ Wt1, _Float16* __restrict__ Wt2,
                       _Float16* __restrict__ Wt3) {
    int i = blockIdx.x * 256 + threadIdx.x;
    if (i < 50048) cnt[i] = 0;
    if (i == 0) {
        int orr = 0;
        for (int j = 0; j < 16; ++j) orr |= ei[2 * j + 1];
        *flag = (orr == 0) ? 1 : 0;
    }
    if (i < 16384) {
        int k = i >> 7, c = i & 127;           // W1[128][128]
        Wt1[c * 128 + k] = (_Float16)W1[i];
    } else if (i < 32768) {
        int j = i - 16384;
        int k = j >> 7, c = j & 127;           // W2[128][128]
        Wt2[c * 128 + k] = (_Float16)W2[j];
    } else if (i < 40960) {
        int j = i - 32768;
        int k = j >> 6, c = j & 63;            // W3[128][64]
        Wt3[c * 128 + k] = (_Float16)W3[j];
    }
}

// Histogram + compact the edge list into 4B packed form (node ids < 2^16).
__global__ void deg_compact_k(const void* ei, const int* flag, int* cnt,
                              unsigned int* __restrict__ ep) {
    int e = blockIdx.x * 256 + threadIdx.x;
    if (e >= N_EDGES) return;
    int is64 = *flag;
    int s, d;
    load_edge(ei, is64, e, s, d);
    ep[e] = (unsigned int)s | ((unsigned int)d << 16);
    atomicAdd(&cnt[d], 1);
}

// Phase 1: per-block local exclusive scan of cnt -> rowptr; dinv fused.
__global__ __launch_bounds__(1024) void scan_pass1_k(const int* __restrict__ cnt,
                                                     int* __restrict__ rowptr,
                                                     int* __restrict__ blocksum,
                                                     float* __restrict__ dinv) {
    __shared__ int buf[1024];
    int tid = threadIdx.x;
    int i = blockIdx.x * 1024 + tid;
    int v = (i < N_NODES) ? cnt[i] : 0;
    if (i < N_NODES) dinv[i] = rsqrtf(1.0f + (float)v);
    buf[tid] = v;
    __syncthreads();
#pragma unroll
    for (int off = 1; off < 1024; off <<= 1) {
        int t = (tid >= off) ? buf[tid - off] : 0;
        __syncthreads();
        buf[tid] += t;
        __syncthreads();
    }
    int incl = buf[tid];
    if (i < N_NODES) rowptr[i] = incl - v;   // local exclusive
    if (tid == 1023) blocksum[blockIdx.x] = incl;
}

// Phase 2+3 merged: every block redundantly wave-scans the 49 block sums,
// then applies its offsets; emits per-bucket reservation cursors.
__global__ void scan_pass23_k(int* __restrict__ rowptr, const int* __restrict__ blocksum,
                              int* __restrict__ bcur) {
    __shared__ int soff[SCAN_BLOCKS];
    int tid = threadIdx.x;
    if (tid < 64) {
        int v = (tid < SCAN_BLOCKS) ? blocksum[tid] : 0;
        int incl = v;
#pragma unroll
        for (int off = 1; off < 64; off <<= 1) {
            int t = __shfl_up(incl, off);
            if (tid >= off) incl += t;
        }
        if (tid < SCAN_BLOCKS) soff[tid] = incl - v;
    }
    __syncthreads();
    int i = blockIdx.x * 256 + tid;
    if (i < N_NODES) {
        int v = rowptr[i] + soff[i >> 10];
        rowptr[i] = v;
        if ((i & (BNODES - 1)) == 0) bcur[i >> BSH] = v;
    }
    if (blockIdx.x == 0 && tid == 0)
        rowptr[N_NODES] = soff[SCAN_BLOCKS - 1] + blocksum[SCAN_BLOCKS - 1];
}

// Bucket pass A: group edges by dst-bucket (128 nodes / bucket).
__global__ __launch_bounds__(256) void bucketA_k(const unsigned int* __restrict__ ep,
                                                 int* bcur,
                                                 unsigned int* __restrict__ ep2) {
    __shared__ int hist[NBKT];
    __shared__ int gofs[NBKT];
    __shared__ int lcur[NBKT];
    int tid = threadIdx.x;
    for (int i = tid; i < NBKT; i += 256) { hist[i] = 0; lcur[i] = 0; }
    __syncthreads();
    int base = blockIdx.x * EPW;
    unsigned int pv[EPW / 256];
#pragma unroll
    for (int j = 0; j < EPW / 256; ++j) {
        int e = base + j * 256 + tid;
        unsigned int p = (e < N_EDGES) ? ep[e] : 0xFFFFFFFFu;
        pv[j] = p;
        if (p != 0xFFFFFFFFu) atomicAdd(&hist[(p >> 16) >> BSH], 1);
    }
    __syncthreads();
    for (int i = tid; i < NBKT; i += 256)
        gofs[i] = hist[i] ? atomicAdd(&bcur[i], hist[i]) : 0;
    __syncthreads();
#pragma unroll
    for (int j = 0; j < EPW / 256; ++j) {
        unsigned int p = pv[j];
        if (p == 0xFFFFFFFFu) continue;
        int b = (int)((p >> 16) >> BSH);
        int pos = gofs[b] + atomicAdd(&lcur[b], 1);
        ep2[pos] = p;
    }
}

// Bucket pass B: one wg per bucket; node cursors in LDS; private 4KB store region.
__global__ __launch_bounds__(256) void bucketB_k(const unsigned int* __restrict__ ep2,
                                                 const int* __restrict__ rowptr,
                                                 unsigned short* __restrict__ csr_src) {
    __shared__ int lcur[BNODES];
    int b = blockIdx.x;
    int lo = b << BSH;
    int hi = min(lo + BNODES, N_NODES);
    int tid = threadIdx.x;
    if (tid < hi - lo) lcur[tid] = rowptr[lo + tid];
    __syncthreads();
    int beg = rowptr[lo];
    int end = rowptr[hi];
    for (int j = beg + tid; j < end; j += 256) {
        unsigned int p = ep2[j];
        int s = (int)(p & 0xFFFFu);
        int d = (int)(p >> 16);
        int slot = atomicAdd(&lcur[d - lo], 1);
        csr_src[slot] = (unsigned short)s;
    }
}

// hs[N][DOUT] = (relu(A)[N][128] @ W[128][DOUT]) * dinv[row], fp16 out.
template <int DOUT, bool RELU, typename TIN>
__global__ __launch_bounds__(256) void mm_mfma_k(const TIN* __restrict__ A,
                                                 const _Float16* __restrict__ Wt,
                                                 const float* __restrict__ dinv,
                                                 _Float16* __restrict__ C) {
    constexpr int AST = 128 + 8;   // padded fp16 row stride (bank-spread)
    __shared__ _Float16 As[64 * AST];
    __shared__ _Float16 Ws[DOUT * AST];
    const int tid = threadIdx.x;
    const int rowBase = blockIdx.x * 64;

    if constexpr (sizeof(TIN) == 4) {
        for (int i = tid; i < 64 * 32; i += 256) {       // float4 granules
            int r = i >> 5;
            int k4 = (i & 31) * 4;
            int gr = rowBase + r;
            float4 v = make_float4(0.f, 0.f, 0.f, 0.f);
            if (gr < N_NODES) v = *(const float4*)((const float*)A + (size_t)gr * 128 + k4);
            if (RELU) {
                v.x = fmaxf(v.x, 0.f); v.y = fmaxf(v.y, 0.f);
                v.z = fmaxf(v.z, 0.f); v.w = fmaxf(v.w, 0.f);
            }
            half4_t hv;
            hv[0] = (_Float16)v.x; hv[1] = (_Float16)v.y;
            hv[2] = (_Float16)v.z; hv[3] = (_Float16)v.w;
            *(half4_t*)&As[r * AST + k4] = hv;
        }
    } else {
        for (int i = tid; i < 64 * 16; i += 256) {       // half8 granules
            int r = i >> 4;
            int k8 = (i & 15) * 8;
            int gr = rowBase + r;
            half8_t v = {};
            if (gr < N_NODES) v = *(const half8_t*)((const _Float16*)A + (size_t)gr * 128 + k8);
            if (RELU) {
#pragma unroll
                for (int j = 0; j < 8; ++j) v[j] = (v[j] > (_Float16)0) ? v[j] : (_Float16)0;
            }
            *(half8_t*)&As[r * AST + k8] = v;
        }
    }
    for (int i = tid; i < DOUT * 16; i += 256) {
        int r = i >> 4;
        int k8 = (i & 15) * 8;
        *(half8_t*)&Ws[r * AST + k8] = *(const half8_t*)(Wt + r * 128 + k8);
    }
    __syncthreads();

    const int wid = tid >> 6;
    const int lane = tid & 63;
    const int l15 = lane & 15;
    const int lk = (lane >> 4) * 8;
    const int wrow = wid * 16;

    floatx4 acc[DOUT / 16];
#pragma unroll
    for (int t = 0; t < DOUT / 16; ++t) acc[t] = (floatx4){0.f, 0.f, 0.f, 0.f};

#pragma unroll
    for (int kc = 0; kc < 4; ++kc) {
        half8_t af = *(const half8_t*)&As[(wrow + l15) * AST + kc * 32 + lk];
#pragma unroll
        for (int ct = 0; ct < DOUT / 16; ++ct) {
            half8_t bf = *(const half8_t*)&Ws[(ct * 16 + l15) * AST + kc * 32 + lk];
            acc[ct] = __builtin_amdgcn_mfma_f32_16x16x32_f16(af, bf, acc[ct], 0, 0, 0);
        }
    }

    int rloc = wrow + (lane >> 4) * 4;
#pragma unroll
    for (int q = 0; q < 4; ++q) {
        int gr = rowBase + rloc + q;
        if (gr < N_NODES) {
            float dn = dinv[gr];
#pragma unroll
            for (int ct = 0; ct < DOUT / 16; ++ct) {
                C[(size_t)gr * DOUT + ct * 16 + l15] = (_Float16)(acc[ct][q] * dn);
            }
        }
    }
}

// Pull aggregation, line-granular column partition:
//   out[n, cols] = dinv[n] * (sum_e hs[src[e], cols] + hs[n, cols]) + b[cols]
// CBF = 32 feats = 64 B = one cache line per node-group per edge.
// cb = blockIdx % NCB; with default round-robin blockIdx->XCD, each XCD's
// slice of h is 50000*64B = 3.2 MB -> fits the 4 MiB private L2.
// Coalescing identical to full-row gather (16x 64B txns/wave).
template <int DOUT, int CBF, bool F16OUT>
__global__ __launch_bounds__(256) void gather_k(const _Float16* __restrict__ h,
                                                const int* __restrict__ rowptr,
                                                const unsigned short* __restrict__ csr_src,
                                                const float* __restrict__ dinv,
                                                const float* __restrict__ b,
                                                void* __restrict__ out) {
    constexpr int TPN = CBF / 8;       // 4 lanes per node
    constexpr int NPB = 256 / TPN;     // 64 nodes per block
    constexpr int NCB = DOUT / CBF;    // 4 (DOUT=128) or 2 (DOUT=64)
    int cb = blockIdx.x % NCB;
    int gb = blockIdx.x / NCB;
    int n = gb * NPB + threadIdx.x / TPN;
    int li = threadIdx.x % TPN;
    if (n >= N_NODES) return;
    int co = cb * CBF + li * 8;        // feature offset of this lane
    const _Float16* hp = h + co;
    int beg = rowptr[n];
    int end = rowptr[n + 1];
    float acc[8], acc2[8];
#pragma unroll
    for (int j = 0; j < 8; ++j) { acc[j] = 0.f; acc2[j] = 0.f; }
    int e = beg;
    for (; e + 4 <= end; e += 4) {
        int s0 = csr_src[e];
        int s1 = csr_src[e + 1];
        int s2 = csr_src[e + 2];
        int s3 = csr_src[e + 3];
        half8_t v0 = *(const half8_t*)(hp + (size_t)s0 * DOUT);
        half8_t v1 = *(const half8_t*)(hp + (size_t)s1 * DOUT);
        half8_t v2 = *(const half8_t*)(hp + (size_t)s2 * DOUT);
        half8_t v3 = *(const half8_t*)(hp + (size_t)s3 * DOUT);
#pragma unroll
        for (int j = 0; j < 8; ++j) {
            acc[j] += (float)v0[j];
            acc2[j] += (float)v1[j];
            acc[j] += (float)v2[j];
            acc2[j] += (float)v3[j];
        }
    }
    for (; e < end; ++e) {
        int s0 = csr_src[e];
        half8_t v0 = *(const half8_t*)(hp + (size_t)s0 * DOUT);
#pragma unroll
        for (int j = 0; j < 8; ++j) acc[j] += (float)v0[j];
    }
    float dn = dinv[n];
    half8_t hv = *(const half8_t*)(hp + (size_t)n * DOUT);
    float4 bv0 = *(const float4*)(b + co);
    float4 bv1 = *(const float4*)(b + co + 4);
    float r[8];
    r[0] = (acc[0] + acc2[0] + (float)hv[0]) * dn + bv0.x;
    r[1] = (acc[1] + acc2[1] + (float)hv[1]) * dn + bv0.y;
    r[2] = (acc[2] + acc2[2] + (float)hv[2]) * dn + bv0.z;
    r[3] = (acc[3] + acc2[3] + (float)hv[3]) * dn + bv0.w;
    r[4] = (acc[4] + acc2[4] + (float)hv[4]) * dn + bv1.x;
    r[5] = (acc[5] + acc2[5] + (float)hv[5]) * dn + bv1.y;
    r[6] = (acc[6] + acc2[6] + (float)hv[6]) * dn + bv1.z;
    r[7] = (acc[7] + acc2[7] + (float)hv[7]) * dn + bv1.w;
    if constexpr (F16OUT) {
        half8_t oV;
#pragma unroll
        for (int j = 0; j < 8; ++j) oV[j] = (_Float16)r[j];
        *(half8_t*)((_Float16*)out + (size_t)n * DOUT + co) = oV;
    } else {
        float* op = (float*)out + (size_t)n * DOUT + co;
        *(float4*)op = make_float4(r[0], r[1], r[2], r[3]);
        *(float4*)(op + 4) = make_float4(r[4], r[5], r[6], r[7]);
    }
}

extern "C" void kernel_launch(void* const* d_in, const int* in_sizes, int n_in,
                              void* d_out, int out_size, void* d_ws, size_t ws_size,
                              hipStream_t stream) {
    const float* x  = (const float*)d_in[0];
    const void*  ei = d_in[1];
    const float* W1 = (const float*)d_in[2];
    const float* b1 = (const float*)d_in[3];
    const float* W2 = (const float*)d_in[4];
    const float* b2 = (const float*)d_in[5];
    const float* W3 = (const float*)d_in[6];
    const float* b3 = (const float*)d_in[7];
    float* out = (float*)d_out;

    char* wsb = (char*)d_ws;
    size_t o = 0;
    int*            flag     = (int*)(wsb + o); o += 64 * 4;
    int*            cnt      = (int*)(wsb + o); o += 50048 * 4;
    float*          dinv     = (float*)(wsb + o); o += 50048 * 4;
    int*            rowptr   = (int*)(wsb + o); o += 50056 * 4;
    int*            blocksum = (int*)(wsb + o); o += 64 * 4;
    int*            bcur     = (int*)(wsb + o); o += 448 * 4;
    unsigned int*   ep       = (unsigned int*)(wsb + o); o += (size_t)N_EDGES * 4;
    unsigned int*   ep2      = (unsigned int*)(wsb + o); o += (size_t)N_EDGES * 4;
    unsigned short* csr_src  = (unsigned short*)(wsb + o); o += (size_t)N_EDGES * 2;
    _Float16*       Wt1      = (_Float16*)(wsb + o); o += 128 * 128 * 2;
    _Float16*       Wt2      = (_Float16*)(wsb + o); o += 128 * 128 * 2;
    _Float16*       Wt3      = (_Float16*)(wsb + o); o += 64 * 128 * 2;
    _Float16*       h        = (_Float16*)(wsb + o); o += (size_t)N_NODES * 128 * 2;
    _Float16*       agg      = (_Float16*)(wsb + o);

    const int NB_N = (N_NODES + 255) / 256;   // 196
    const int NB_E = (N_EDGES + 255) / 256;   // 3125
    const int MMB  = (N_NODES + 63) / 64;     // 782
    const int G128 = 4 * ((N_NODES + 63) / 64);   // NCB=4, 64 nodes/block
    const int G64  = 2 * ((N_NODES + 63) / 64);   // NCB=2

    // ---- graph preprocessing (once; reused by all 3 layers) ----
    init_k<<<NB_N, 256, 0, stream>>>((const int*)ei, flag, cnt, W1, W2, W3, Wt1, Wt2, Wt3);
    deg_compact_k<<<NB_E, 256, 0, stream>>>(ei, flag, cnt, ep);
    scan_pass1_k<<<SCAN_BLOCKS, 1024, 0, stream>>>(cnt, rowptr, blocksum, dinv);
    scan_pass23_k<<<NB_N, 256, 0, stream>>>(rowptr, blocksum, bcur);
    bucketA_k<<<NWG_A, 256, 0, stream>>>(ep, bcur, ep2);
    bucketB_k<<<NBKT, 256, 0, stream>>>(ep2, rowptr, csr_src);

    // ---- layer 1 ----
    mm_mfma_k<128, false, float><<<MMB, 256, 0, stream>>>(x, Wt1, dinv, h);
    gather_k<128, 32, true><<<G128, 256, 0, stream>>>(h, rowptr, csr_src, dinv, b1, agg);

    // ---- layer 2 ----
    mm_mfma_k<128, true, _Float16><<<MMB, 256, 0, stream>>>(agg, Wt2, dinv, h);
    gather_k<128, 32, true><<<G128, 256, 0, stream>>>(h, rowptr, csr_src, dinv, b2, agg);

    // ---- layer 3 (to d_out, f32) ----
    mm_mfma_k<64, true, _Float16><<<MMB, 256, 0, stream>>>(agg, Wt3, dinv, h);
    gather_k<64, 32, false><<<G64, 256, 0, stream>>>(h, rowptr, csr_src, dinv, b3, out);
}

// Round 12
// 209.348 us; speedup vs baseline: 1.5884x; 1.4029x over previous
//
#include <hip/hip_runtime.h>
#include <math.h>

#define N_NODES 50000
#define N_EDGES 800000
#define SCAN_BLOCKS ((N_NODES + 1023) / 1024)   // 49
#define BSH 7                                    // 128 nodes per bucket
#define BNODES 128
#define NBKT ((N_NODES + BNODES - 1) / BNODES)   // 391
#define EPW 4096                                 // edges per workgroup in bucketA
#define NWG_A ((N_EDGES + EPW - 1) / EPW)        // 196

typedef _Float16 half4_t __attribute__((ext_vector_type(4)));
typedef _Float16 half8_t __attribute__((ext_vector_type(8)));
typedef float floatx4 __attribute__((ext_vector_type(4)));

// ---------------------------------------------------------------------------
// Workspace layout:
//   flag     : int[64]
//   cnt      : int[50048]    in-degree (no self-loop)
//   dinv     : float[50048]  rsqrt(1+deg)
//   rowptr   : int[50056]    global exclusive scan
//   blocksum : int[64]
//   bcur     : int[448]      per-bucket reservation cursors
//   ep       : uint[800000]  packed edges (src | dst<<16)
//   ep2      : uint[800000]  bucket-grouped packed edges
//   csr_src  : ushort[800000]
//   Wt1/2/3  : fp16 W^T
//   h        : fp16[50000*128]
//   agg      : fp16[50000*128]
//
// NOTE (r10/r11 lesson): column-partitioned gathers (CBF=16/8 and CBF=32)
// both REGRESSED vs full-row: FETCH_SIZE rose ~4x because the same h-rows'
// cache lines get fetched at 4 different times by different blocks, and h
// (12.8MB) doesn't stay resident in a 4MiB XCD L2. blockIdx->XCD slice
// residency is NOT realizable (mapping undefined). Keep full-row gathers.
// ---------------------------------------------------------------------------

__device__ __forceinline__ void load_edge(const void* ei, int is64, int e, int& s, int& d) {
    if (is64) {
        const long long* q = (const long long*)ei;
        s = (int)q[e];
        d = (int)q[N_EDGES + e];
    } else {
        const int* q = (const int*)ei;
        s = q[e];
        d = q[N_EDGES + e];
    }
}

// Merged: zero cnt + detect i64 + weight cast/transpose.
__global__ void init_k(const int* ei, int* flag, int* cnt,
                       const float* __restrict__ W1, const float* __restrict__ W2,
                       const float* __restrict__ W3,
                       _Float16* __restrict__ Wt1, _Float16* __restrict__ Wt2,
                       _Float16* __restrict__ Wt3) {
    int i = blockIdx.x * 256 + threadIdx.x;
    if (i < 50048) cnt[i] = 0;
    if (i == 0) {
        int orr = 0;
        for (int j = 0; j < 16; ++j) orr |= ei[2 * j + 1];
        *flag = (orr == 0) ? 1 : 0;
    }
    if (i < 16384) {
        int k = i >> 7, c = i & 127;           // W1[128][128]
        Wt1[c * 128 + k] = (_Float16)W1[i];
    } else if (i < 32768) {
        int j = i - 16384;
        int k = j >> 7, c = j & 127;           // W2[128][128]
        Wt2[c * 128 + k] = (_Float16)W2[j];
    } else if (i < 40960) {
        int j = i - 32768;
        int k = j >> 6, c = j & 63;            // W3[128][64]
        Wt3[c * 128 + k] = (_Float16)W3[j];
    }
}

// Histogram + compact the edge list into 4B packed form (node ids < 2^16).
__global__ void deg_compact_k(const void* ei, const int* flag, int* cnt,
                              unsigned int* __restrict__ ep) {
    int e = blockIdx.x * 256 + threadIdx.x;
    if (e >= N_EDGES) return;
    int is64 = *flag;
    int s, d;
    load_edge(ei, is64, e, s, d);
    ep[e] = (unsigned int)s | ((unsigned int)d << 16);
    atomicAdd(&cnt[d], 1);
}

// Phase 1: per-block local exclusive scan of cnt -> rowptr; dinv fused.
__global__ __launch_bounds__(1024) void scan_pass1_k(const int* __restrict__ cnt,
                                                     int* __restrict__ rowptr,
                                                     int* __restrict__ blocksum,
                                                     float* __restrict__ dinv) {
    __shared__ int buf[1024];
    int tid = threadIdx.x;
    int i = blockIdx.x * 1024 + tid;
    int v = (i < N_NODES) ? cnt[i] : 0;
    if (i < N_NODES) dinv[i] = rsqrtf(1.0f + (float)v);
    buf[tid] = v;
    __syncthreads();
#pragma unroll
    for (int off = 1; off < 1024; off <<= 1) {
        int t = (tid >= off) ? buf[tid - off] : 0;
        __syncthreads();
        buf[tid] += t;
        __syncthreads();
    }
    int incl = buf[tid];
    if (i < N_NODES) rowptr[i] = incl - v;   // local exclusive
    if (tid == 1023) blocksum[blockIdx.x] = incl;
}

// Phase 2+3 merged: every block redundantly wave-scans the 49 block sums,
// then applies its offsets; emits per-bucket reservation cursors.
__global__ void scan_pass23_k(int* __restrict__ rowptr, const int* __restrict__ blocksum,
                              int* __restrict__ bcur) {
    __shared__ int soff[SCAN_BLOCKS];
    int tid = threadIdx.x;
    if (tid < 64) {
        int v = (tid < SCAN_BLOCKS) ? blocksum[tid] : 0;
        int incl = v;
#pragma unroll
        for (int off = 1; off < 64; off <<= 1) {
            int t = __shfl_up(incl, off);
            if (tid >= off) incl += t;
        }
        if (tid < SCAN_BLOCKS) soff[tid] = incl - v;
    }
    __syncthreads();
    int i = blockIdx.x * 256 + tid;
    if (i < N_NODES) {
        int v = rowptr[i] + soff[i >> 10];
        rowptr[i] = v;
        if ((i & (BNODES - 1)) == 0) bcur[i >> BSH] = v;
    }
    if (blockIdx.x == 0 && tid == 0)
        rowptr[N_NODES] = soff[SCAN_BLOCKS - 1] + blocksum[SCAN_BLOCKS - 1];
}

// Bucket pass A: group edges by dst-bucket (128 nodes / bucket).
__global__ __launch_bounds__(256) void bucketA_k(const unsigned int* __restrict__ ep,
                                                 int* bcur,
                                                 unsigned int* __restrict__ ep2) {
    __shared__ int hist[NBKT];
    __shared__ int gofs[NBKT];
    __shared__ int lcur[NBKT];
    int tid = threadIdx.x;
    for (int i = tid; i < NBKT; i += 256) { hist[i] = 0; lcur[i] = 0; }
    __syncthreads();
    int base = blockIdx.x * EPW;
    unsigned int pv[EPW / 256];
#pragma unroll
    for (int j = 0; j < EPW / 256; ++j) {
        int e = base + j * 256 + tid;
        unsigned int p = (e < N_EDGES) ? ep[e] : 0xFFFFFFFFu;
        pv[j] = p;
        if (p != 0xFFFFFFFFu) atomicAdd(&hist[(p >> 16) >> BSH], 1);
    }
    __syncthreads();
    for (int i = tid; i < NBKT; i += 256)
        gofs[i] = hist[i] ? atomicAdd(&bcur[i], hist[i]) : 0;
    __syncthreads();
#pragma unroll
    for (int j = 0; j < EPW / 256; ++j) {
        unsigned int p = pv[j];
        if (p == 0xFFFFFFFFu) continue;
        int b = (int)((p >> 16) >> BSH);
        int pos = gofs[b] + atomicAdd(&lcur[b], 1);
        ep2[pos] = p;
    }
}

// Bucket pass B: one wg per bucket; node cursors in LDS; private 4KB store region.
__global__ __launch_bounds__(256) void bucketB_k(const unsigned int* __restrict__ ep2,
                                                 const int* __restrict__ rowptr,
                                                 unsigned short* __restrict__ csr_src) {
    __shared__ int lcur[BNODES];
    int b = blockIdx.x;
    int lo = b << BSH;
    int hi = min(lo + BNODES, N_NODES);
    int tid = threadIdx.x;
    if (tid < hi - lo) lcur[tid] = rowptr[lo + tid];
    __syncthreads();
    int beg = rowptr[lo];
    int end = rowptr[hi];
    for (int j = beg + tid; j < end; j += 256) {
        unsigned int p = ep2[j];
        int s = (int)(p & 0xFFFFu);
        int d = (int)(p >> 16);
        int slot = atomicAdd(&lcur[d - lo], 1);
        csr_src[slot] = (unsigned short)s;
    }
}

// hs[N][DOUT] = (relu(A)[N][128] @ W[128][DOUT]) * dinv[row], fp16 out.
template <int DOUT, bool RELU, typename TIN>
__global__ __launch_bounds__(256) void mm_mfma_k(const TIN* __restrict__ A,
                                                 const _Float16* __restrict__ Wt,
                                                 const float* __restrict__ dinv,
                                                 _Float16* __restrict__ C) {
    constexpr int AST = 128 + 8;   // padded fp16 row stride (bank-spread)
    __shared__ _Float16 As[64 * AST];
    __shared__ _Float16 Ws[DOUT * AST];
    const int tid = threadIdx.x;
    const int rowBase = blockIdx.x * 64;

    if constexpr (sizeof(TIN) == 4) {
        for (int i = tid; i < 64 * 32; i += 256) {       // float4 granules
            int r = i >> 5;
            int k4 = (i & 31) * 4;
            int gr = rowBase + r;
            float4 v = make_float4(0.f, 0.f, 0.f, 0.f);
            if (gr < N_NODES) v = *(const float4*)((const float*)A + (size_t)gr * 128 + k4);
            if (RELU) {
                v.x = fmaxf(v.x, 0.f); v.y = fmaxf(v.y, 0.f);
                v.z = fmaxf(v.z, 0.f); v.w = fmaxf(v.w, 0.f);
            }
            half4_t hv;
            hv[0] = (_Float16)v.x; hv[1] = (_Float16)v.y;
            hv[2] = (_Float16)v.z; hv[3] = (_Float16)v.w;
            *(half4_t*)&As[r * AST + k4] = hv;
        }
    } else {
        for (int i = tid; i < 64 * 16; i += 256) {       // half8 granules
            int r = i >> 4;
            int k8 = (i & 15) * 8;
            int gr = rowBase + r;
            half8_t v = {};
            if (gr < N_NODES) v = *(const half8_t*)((const _Float16*)A + (size_t)gr * 128 + k8);
            if (RELU) {
#pragma unroll
                for (int j = 0; j < 8; ++j) v[j] = (v[j] > (_Float16)0) ? v[j] : (_Float16)0;
            }
            *(half8_t*)&As[r * AST + k8] = v;
        }
    }
    for (int i = tid; i < DOUT * 16; i += 256) {
        int r = i >> 4;
        int k8 = (i & 15) * 8;
        *(half8_t*)&Ws[r * AST + k8] = *(const half8_t*)(Wt + r * 128 + k8);
    }
    __syncthreads();

    const int wid = tid >> 6;
    const int lane = tid & 63;
    const int l15 = lane & 15;
    const int lk = (lane >> 4) * 8;
    const int wrow = wid * 16;

    floatx4 acc[DOUT / 16];
#pragma unroll
    for (int t = 0; t < DOUT / 16; ++t) acc[t] = (floatx4){0.f, 0.f, 0.f, 0.f};

#pragma unroll
    for (int kc = 0; kc < 4; ++kc) {
        half8_t af = *(const half8_t*)&As[(wrow + l15) * AST + kc * 32 + lk];
#pragma unroll
        for (int ct = 0; ct < DOUT / 16; ++ct) {
            half8_t bf = *(const half8_t*)&Ws[(ct * 16 + l15) * AST + kc * 32 + lk];
            acc[ct] = __builtin_amdgcn_mfma_f32_16x16x32_f16(af, bf, acc[ct], 0, 0, 0);
        }
    }

    int rloc = wrow + (lane >> 4) * 4;
#pragma unroll
    for (int q = 0; q < 4; ++q) {
        int gr = rowBase + rloc + q;
        if (gr < N_NODES) {
            float dn = dinv[gr];
#pragma unroll
            for (int ct = 0; ct < DOUT / 16; ++ct) {
                C[(size_t)gr * DOUT + ct * 16 + l15] = (_Float16)(acc[ct][q] * dn);
            }
        }
    }
}

// Pull aggregation (FULL-ROW, proven form):
//   out[n] = dinv[n] * (sum_e hs[src[e]] + hs[n]) + b
// TPN = DOUT/8 lanes per node, each lane loads half8 (16B); a node-group's
// lanes cover the whole row -> each row's lines fetched once, used fully.
// 8-way edge unroll: 8 independent 16B gathers in flight per lane.
template <int DOUT, bool F16OUT>
__global__ __launch_bounds__(256) void gather_k(const _Float16* __restrict__ h,
                                                const int* __restrict__ rowptr,
                                                const unsigned short* __restrict__ csr_src,
                                                const float* __restrict__ dinv,
                                                const float* __restrict__ b,
                                                void* __restrict__ out) {
    constexpr int TPN = DOUT / 8;
    constexpr int NPB = 256 / TPN;
    int n = blockIdx.x * NPB + threadIdx.x / TPN;
    int li = threadIdx.x % TPN;
    if (n >= N_NODES) return;
    const _Float16* hp = h + li * 8;
    int beg = rowptr[n];
    int end = rowptr[n + 1];
    float acc[8], acc2[8];
#pragma unroll
    for (int j = 0; j < 8; ++j) { acc[j] = 0.f; acc2[j] = 0.f; }
    int e = beg;
    for (; e + 8 <= end; e += 8) {
        int s0 = csr_src[e];
        int s1 = csr_src[e + 1];
        int s2 = csr_src[e + 2];
        int s3 = csr_src[e + 3];
        int s4 = csr_src[e + 4];
        int s5 = csr_src[e + 5];
        int s6 = csr_src[e + 6];
        int s7 = csr_src[e + 7];
        half8_t v0 = *(const half8_t*)(hp + (size_t)s0 * DOUT);
        half8_t v1 = *(const half8_t*)(hp + (size_t)s1 * DOUT);
        half8_t v2 = *(const half8_t*)(hp + (size_t)s2 * DOUT);
        half8_t v3 = *(const half8_t*)(hp + (size_t)s3 * DOUT);
        half8_t v4 = *(const half8_t*)(hp + (size_t)s4 * DOUT);
        half8_t v5 = *(const half8_t*)(hp + (size_t)s5 * DOUT);
        half8_t v6 = *(const half8_t*)(hp + (size_t)s6 * DOUT);
        half8_t v7 = *(const half8_t*)(hp + (size_t)s7 * DOUT);
#pragma unroll
        for (int j = 0; j < 8; ++j) {
            acc[j] += (float)v0[j];
            acc2[j] += (float)v1[j];
            acc[j] += (float)v2[j];
            acc2[j] += (float)v3[j];
            acc[j] += (float)v4[j];
            acc2[j] += (float)v5[j];
            acc[j] += (float)v6[j];
            acc2[j] += (float)v7[j];
        }
    }
    for (; e + 2 <= end; e += 2) {
        int s0 = csr_src[e];
        int s1 = csr_src[e + 1];
        half8_t v0 = *(const half8_t*)(hp + (size_t)s0 * DOUT);
        half8_t v1 = *(const half8_t*)(hp + (size_t)s1 * DOUT);
#pragma unroll
        for (int j = 0; j < 8; ++j) {
            acc[j] += (float)v0[j];
            acc2[j] += (float)v1[j];
        }
    }
    if (e < end) {
        int s0 = csr_src[e];
        half8_t v0 = *(const half8_t*)(hp + (size_t)s0 * DOUT);
#pragma unroll
        for (int j = 0; j < 8; ++j) acc[j] += (float)v0[j];
    }
    float dn = dinv[n];
    half8_t hv = *(const half8_t*)(hp + (size_t)n * DOUT);
    float4 bv0 = *(const float4*)(b + li * 8);
    float4 bv1 = *(const float4*)(b + li * 8 + 4);
    float r[8];
    r[0] = (acc[0] + acc2[0] + (float)hv[0]) * dn + bv0.x;
    r[1] = (acc[1] + acc2[1] + (float)hv[1]) * dn + bv0.y;
    r[2] = (acc[2] + acc2[2] + (float)hv[2]) * dn + bv0.z;
    r[3] = (acc[3] + acc2[3] + (float)hv[3]) * dn + bv0.w;
    r[4] = (acc[4] + acc2[4] + (float)hv[4]) * dn + bv1.x;
    r[5] = (acc[5] + acc2[5] + (float)hv[5]) * dn + bv1.y;
    r[6] = (acc[6] + acc2[6] + (float)hv[6]) * dn + bv1.z;
    r[7] = (acc[7] + acc2[7] + (float)hv[7]) * dn + bv1.w;
    if constexpr (F16OUT) {
        half8_t oV;
#pragma unroll
        for (int j = 0; j < 8; ++j) oV[j] = (_Float16)r[j];
        *(half8_t*)((_Float16*)out + (size_t)n * DOUT + li * 8) = oV;
    } else {
        float* op = (float*)out + (size_t)n * DOUT + li * 8;
        *(float4*)op = make_float4(r[0], r[1], r[2], r[3]);
        *(float4*)(op + 4) = make_float4(r[4], r[5], r[6], r[7]);
    }
}

extern "C" void kernel_launch(void* const* d_in, const int* in_sizes, int n_in,
                              void* d_out, int out_size, void* d_ws, size_t ws_size,
                              hipStream_t stream) {
    const float* x  = (const float*)d_in[0];
    const void*  ei = d_in[1];
    const float* W1 = (const float*)d_in[2];
    const float* b1 = (const float*)d_in[3];
    const float* W2 = (const float*)d_in[4];
    const float* b2 = (const float*)d_in[5];
    const float* W3 = (const float*)d_in[6];
    const float* b3 = (const float*)d_in[7];
    float* out = (float*)d_out;

    char* wsb = (char*)d_ws;
    size_t o = 0;
    int*            flag     = (int*)(wsb + o); o += 64 * 4;
    int*            cnt      = (int*)(wsb + o); o += 50048 * 4;
    float*          dinv     = (float*)(wsb + o); o += 50048 * 4;
    int*            rowptr   = (int*)(wsb + o); o += 50056 * 4;
    int*            blocksum = (int*)(wsb + o); o += 64 * 4;
    int*            bcur     = (int*)(wsb + o); o += 448 * 4;
    unsigned int*   ep       = (unsigned int*)(wsb + o); o += (size_t)N_EDGES * 4;
    unsigned int*   ep2      = (unsigned int*)(wsb + o); o += (size_t)N_EDGES * 4;
    unsigned short* csr_src  = (unsigned short*)(wsb + o); o += (size_t)N_EDGES * 2;
    _Float16*       Wt1      = (_Float16*)(wsb + o); o += 128 * 128 * 2;
    _Float16*       Wt2      = (_Float16*)(wsb + o); o += 128 * 128 * 2;
    _Float16*       Wt3      = (_Float16*)(wsb + o); o += 64 * 128 * 2;
    _Float16*       h        = (_Float16*)(wsb + o); o += (size_t)N_NODES * 128 * 2;
    _Float16*       agg      = (_Float16*)(wsb + o);

    const int NB_N = (N_NODES + 255) / 256;   // 196
    const int NB_E = (N_EDGES + 255) / 256;   // 3125
    const int MMB  = (N_NODES + 63) / 64;     // 782

    // ---- graph preprocessing (once; reused by all 3 layers) ----
    init_k<<<NB_N, 256, 0, stream>>>((const int*)ei, flag, cnt, W1, W2, W3, Wt1, Wt2, Wt3);
    deg_compact_k<<<NB_E, 256, 0, stream>>>(ei, flag, cnt, ep);
    scan_pass1_k<<<SCAN_BLOCKS, 1024, 0, stream>>>(cnt, rowptr, blocksum, dinv);
    scan_pass23_k<<<NB_N, 256, 0, stream>>>(rowptr, blocksum, bcur);
    bucketA_k<<<NWG_A, 256, 0, stream>>>(ep, bcur, ep2);
    bucketB_k<<<NBKT, 256, 0, stream>>>(ep2, rowptr, csr_src);

    // ---- layer 1 ----
    mm_mfma_k<128, false, float><<<MMB, 256, 0, stream>>>(x, Wt1, dinv, h);
    gather_k<128, true><<<(N_NODES + 15) / 16, 256, 0, stream>>>(h, rowptr, csr_src, dinv, b1, agg);

    // ---- layer 2 ----
    mm_mfma_k<128, true, _Float16><<<MMB, 256, 0, stream>>>(agg, Wt2, dinv, h);
    gather_k<128, true><<<(N_NODES + 15) / 16, 256, 0, stream>>>(h, rowptr, csr_src, dinv, b2, agg);

    // ---- layer 3 (to d_out, f32) ----
    mm_mfma_k<64, true, _Float16><<<MMB, 256, 0, stream>>>(agg, Wt3, dinv, h);
    gather_k<64, false><<<(N_NODES + 31) / 32, 256, 0, stream>>>(h, rowptr, csr_src, dinv, b3, out);
}